// Round 5
// baseline (112.210 us; speedup 1.0000x reference)
//
#include <hip/hip_runtime.h>
#include <hip/hip_bf16.h>

// Problem constants
#define N_IN   65536
#define N_OUTP 16384
#define KNB    16
#define FDIM   64
#define M_DIM  32          // N_DIST * N_PHI
#define KDIM   2048        // M_DIM * FDIM
#define OUT_D  256

typedef __bf16 bf16x8_t __attribute__((ext_vector_type(8)));
typedef float  f32x4_t  __attribute__((ext_vector_type(4)));

// ---------------------------------------------------------------------------
// A storage ("stream" layout): per 16-row tile T (=row>>4), per K32-chunk kk,
// 64 lanes x 16B. Lane l holds rows (l&15), kg in [kk*32+(l>>4)*8, +8).
// u128 index = T*4096 + kk*64 + l.  Total 1024 tiles * 64KB = 64 MB.
// ---------------------------------------------------------------------------

// ---------------------------------------------------------------------------
// pack_B: W_out (2048x256 f32) -> bf16 B-fragments. Chunk c = (kk, nt, lane);
// lane l holds B[kk*32 + (l>>4)*8 + j][nt*16 + (l&15)], j = 0..7.
// ---------------------------------------------------------------------------
__global__ __launch_bounds__(256) void pack_B_kernel(
    const float* __restrict__ W, uint4* __restrict__ Bws)
{
  int c    = blockIdx.x * 256 + threadIdx.x;   // 65536 chunks
  int lane = c & 63;
  int nt   = (c >> 6) & 15;
  int kk   = c >> 10;
  int row0 = kk * 32 + (lane >> 4) * 8;
  int col  = nt * 16 + (lane & 15);
  union { unsigned short s[8]; uint4 v; } u;
#pragma unroll
  for (int j = 0; j < 8; ++j) {
    float f = W[(row0 + j) * OUT_D + col];
    __bf16 b = (__bf16)f;
    u.s[j] = __builtin_bit_cast(unsigned short, b);
  }
  Bws[c] = u.v;
}

// ---------------------------------------------------------------------------
// agg: weights + gather(x -> LDS) + 8x8-tiled einsum + normalize ->
// A in fragment-stream layout. 8 rows/block, 2048 blocks, 256 threads.
// LDS 52.7 KB -> 3 blocks/CU. pkbuf overlays xbuf (union).
// xbuf row = 68 floats: f 0..31 at [0..32), f 32..63 at [36..68) (bank pad).
// ---------------------------------------------------------------------------
#define AGG_ROWS 8
#define XK  68
#define XR8 (16 * XK)     // 1088 floats per r8

__global__ __launch_bounds__(256) void agg_kernel(
    const float* __restrict__ x,
    const float* __restrict__ d_dists,
    const float* __restrict__ d_phi,
    const float* __restrict__ dists,
    const float* __restrict__ sigma_p,
    const float* __restrict__ kappa_p,
    const float* __restrict__ phi,
    const int*   __restrict__ nh_idx,
    unsigned*    __restrict__ Aws)     // stream layout, u32 = 2 packed bf16
{
  __shared__ float wbuf[AGG_ROWS * 16 * 32];            // 16 KB
  __shared__ float winv[AGG_ROWS * 32];                 // 1 KB
  __shared__ int   idxb[AGG_ROWS * 16];
  __shared__ __align__(16) char xpk_raw[AGG_ROWS * XR8 * 4];  // 34.8 KB union
  float*    xbuf  = (float*)xpk_raw;
  unsigned* pkbuf = (unsigned*)xpk_raw;                 // [8][1028] fits

  const int t  = threadIdx.x;
  const int n0 = blockIdx.x * AGG_ROWS;
  const int T  = blockIdx.x >> 1;          // 16-row tile index
  const int r0 = (blockIdx.x & 1) * 8;     // row offset within tile

  const float sinv = 1.0f / sigma_p[0];
  const float kap  = kappa_p[0];
  float phiv[8], distv[4];
#pragma unroll
  for (int p = 0; p < 8; ++p) phiv[p] = phi[p];
#pragma unroll
  for (int d = 0; d < 4; ++d) distv[d] = dists[d];

  // Phase 1 — weights: thread -> (r8 = (t>>1)>>4, k = (t>>1)&15, rep = t&1)
  {
    int rk = t >> 1, r8 = rk >> 4, k = rk & 15, rep = t & 1;
    int n = n0 + r8;
    float dd = d_dists[n * KNB + k];
    float dp = d_phi[n * KNB + k];
    float wp[8];
#pragma unroll
    for (int p = 0; p < 8; ++p) wp[p] = __expf(kap * __cosf(dp - phiv[p]));
#pragma unroll
    for (int dl = 0; dl < 2; ++dl) {
      int d = rep * 2 + dl;
      float td = (dd - distv[d]) * sinv;
      float wd = __expf(-0.5f * td * td);
      float4 w0 = make_float4(wd * wp[0], wd * wp[1], wd * wp[2], wd * wp[3]);
      float4 w1 = make_float4(wd * wp[4], wd * wp[5], wd * wp[6], wd * wp[7]);
      float* dst = wbuf + (r8 * 16 + k) * 32 + d * 8;
      *(float4*)(dst)     = w0;
      *(float4*)(dst + 4) = w1;
    }
    if (t < 128) {
      int r8b = t >> 4, kb = t & 15;
      idxb[r8b * 16 + kb] = nh_idx[(n0 + r8b) * KNB + kb];
    }
  }
  __syncthreads();

  // Phase 2 — gather x rows into xbuf (coalesced), then winv.
  {
    int h = t & 1, k = (t >> 1) & 15, r8 = t >> 5;
    int idx = idxb[r8 * 16 + k];
    const float4* xr = (const float4*)x + (size_t)idx * 16 + h * 8;
    float4* xd = (float4*)(xbuf + r8 * XR8 + k * XK + h * 36);
#pragma unroll
    for (int j = 0; j < 8; ++j) xd[j] = xr[j];
  }
  {
    int r8 = t >> 5, m = t & 31;
    float s = 0.f;
#pragma unroll
    for (int k = 0; k < 16; ++k) s += wbuf[(r8 * 16 + k) * 32 + m];
    winv[r8 * 32 + m] = 1.0f / (s + 1e-9f);
  }
  __syncthreads();

  // Phase 3 — einsum, 8m x 8f per thread: (fg = t&7, mg = (t>>3)&3, r8 = t>>5)
  float acc[8][8];
  const int fg = t & 7, mg = (t >> 3) & 3, r8 = t >> 5;
  {
#pragma unroll
    for (int mi = 0; mi < 8; ++mi)
#pragma unroll
      for (int fi = 0; fi < 8; ++fi) acc[mi][fi] = 0.f;

    const float* wp_ = wbuf + r8 * 512 + mg * 8;
    const float* xp_ = xbuf + r8 * XR8 + ((fg < 4) ? fg * 8 : 36 + (fg - 4) * 8);

#pragma unroll
    for (int k = 0; k < 16; ++k) {
      float4 wa = *(const float4*)(wp_ + k * 32);
      float4 wb = *(const float4*)(wp_ + k * 32 + 4);
      float4 xa = *(const float4*)(xp_ + k * XK);
      float4 xb = *(const float4*)(xp_ + k * XK + 4);
      float wv[8] = {wa.x, wa.y, wa.z, wa.w, wb.x, wb.y, wb.z, wb.w};
      float xv[8] = {xa.x, xa.y, xa.z, xa.w, xb.x, xb.y, xb.z, xb.w};
#pragma unroll
      for (int mi = 0; mi < 8; ++mi)
#pragma unroll
        for (int fi = 0; fi < 8; ++fi)
          acc[mi][fi] += wv[mi] * xv[fi];
    }
    // normalize by m
#pragma unroll
    for (int mi = 0; mi < 8; ++mi) {
      float wn = winv[r8 * 32 + mg * 8 + mi];
#pragma unroll
      for (int fi = 0; fi < 8; ++fi) acc[mi][fi] *= wn;
    }
  }
  __syncthreads();   // xbuf dead; pkbuf overlays it

  // Phase 4 — pack bf16 pairs into pkbuf (transpose staging).
  // kidx = m*32 + fp, m = mg*8+mi, fp = fg*4+fi2. mg-staggered fi2 order
  // keeps writes conflict-free.
  {
    unsigned* pb = pkbuf + r8 * 1028 + (mg * 8) * 32 + fg * 4;
#pragma unroll
    for (int jj = 0; jj < 4; ++jj) {
      int fi2 = (jj + mg) & 3;
#pragma unroll
      for (int mi = 0; mi < 8; ++mi) {
        __bf16 b0 = (__bf16)acc[mi][fi2 * 2];
        __bf16 b1 = (__bf16)acc[mi][fi2 * 2 + 1];
        unsigned pk = ((unsigned)__builtin_bit_cast(unsigned short, b1) << 16)
                    |  (unsigned)__builtin_bit_cast(unsigned short, b0);
        pb[mi * 32 + fi2] = pk;
      }
    }
  }
  __syncthreads();

  // Phase 5 — coalesced copy-out to stream layout:
  // global u32 idx = T*16384 + kk*256 + ks*64 + (r0+rr)*4 + b,
  // holding kidx = kk*16 + ks*4 + b of row (r0+rr).
  {
    int b   = t & 3;
    int rr  = (t >> 2) & 7;
    int ks  = (t >> 5) & 3;
    int kks = t >> 7;                      // 0 or 1
    unsigned* g = Aws + (size_t)T * 16384 + ks * 64 + (r0 + rr) * 4 + b;
    const unsigned* src = pkbuf + rr * 1028 + ks * 4 + b;
#pragma unroll
    for (int i = 0; i < 32; ++i) {
      int kk = kks * 32 + i;
      g[kk * 256] = src[kk * 16];
    }
  }
}

// ---------------------------------------------------------------------------
// gemm: out(16384x256) = A(stream) @ B(frags). 256 blocks x 512 threads.
// Block = 64 rows x 256 cols; wave w: rows (w&1)*32, cols (w>>1)*64.
// No LDS, no barriers, no atomics. Depth-2 register double-buffer.
// ---------------------------------------------------------------------------
__global__ __launch_bounds__(512) void gemm_kernel(
    const uint4* __restrict__ Astream,
    const uint4* __restrict__ Bws,
    float*       __restrict__ out)
{
  const int t    = threadIdx.x;
  const int lane = t & 63;
  const int w    = t >> 6;
  const int rb   = blockIdx.x;

  const uint4* pa = Astream + (size_t)(rb * 4 + (w & 1) * 2) * 4096 + lane;
  const uint4* pb = Bws + ((w >> 1) * 4) * 64 + lane;

  f32x4_t cacc[2][4];
#pragma unroll
  for (int mt = 0; mt < 2; ++mt)
#pragma unroll
    for (int i = 0; i < 4; ++i)
      cacc[mt][i] = (f32x4_t){0.f, 0.f, 0.f, 0.f};

  uint4 a[2][2], b[2][4];
#pragma unroll
  for (int s = 0; s < 2; ++s) {
    a[s][0] = pa[s * 64];
    a[s][1] = pa[4096 + s * 64];
#pragma unroll
    for (int i = 0; i < 4; ++i) b[s][i] = pb[s * 1024 + i * 64];
  }

#pragma unroll 4
  for (int kk = 0; kk < 64; ++kk) {
    const int s = kk & 1;
    bf16x8_t A0 = __builtin_bit_cast(bf16x8_t, a[s][0]);
    bf16x8_t A1 = __builtin_bit_cast(bf16x8_t, a[s][1]);
#pragma unroll
    for (int i = 0; i < 4; ++i) {
      bf16x8_t B = __builtin_bit_cast(bf16x8_t, b[s][i]);
      cacc[0][i] = __builtin_amdgcn_mfma_f32_16x16x32_bf16(A0, B, cacc[0][i], 0, 0, 0);
      cacc[1][i] = __builtin_amdgcn_mfma_f32_16x16x32_bf16(A1, B, cacc[1][i], 0, 0, 0);
    }
    if (kk < 62) {
      a[s][0] = pa[(kk + 2) * 64];
      a[s][1] = pa[4096 + (kk + 2) * 64];
#pragma unroll
      for (int i = 0; i < 4; ++i) b[s][i] = pb[(kk + 2) * 1024 + i * 64];
    }
  }

  // C/D layout: col = lane&15, row = (lane>>4)*4 + reg
  const int rbase = rb * 64 + (w & 1) * 32 + (lane >> 4) * 4;
  const int cbase = (w >> 1) * 64 + (lane & 15);
#pragma unroll
  for (int mt = 0; mt < 2; ++mt)
#pragma unroll
    for (int i = 0; i < 4; ++i)
#pragma unroll
      for (int reg = 0; reg < 4; ++reg)
        out[(rbase + mt * 16 + reg) * OUT_D + cbase + i * 16] = cacc[mt][i][reg];
}

// ===========================================================================
extern "C" void kernel_launch(void* const* d_in, const int* in_sizes, int n_in,
                              void* d_out, int out_size, void* d_ws, size_t ws_size,
                              hipStream_t stream) {
  const float* x      = (const float*)d_in[0];
  const float* dd     = (const float*)d_in[1];
  const float* dp     = (const float*)d_in[2];
  const float* dists  = (const float*)d_in[3];
  const float* sigma  = (const float*)d_in[4];
  const float* kappa  = (const float*)d_in[5];
  const float* phi    = (const float*)d_in[6];
  const float* W      = (const float*)d_in[7];
  const int*   nh     = (const int*)d_in[8];
  float*       out    = (float*)d_out;

  uint4* Bws = (uint4*)d_ws;                       // 1 MB of B-fragments
  uint4* Aws = (uint4*)((char*)d_ws + (1 << 20));  // 64 MB A, stream layout

  pack_B_kernel<<<256, 256, 0, stream>>>(W, Bws);
  agg_kernel<<<N_OUTP / AGG_ROWS, 256, 0, stream>>>(
      x, dd, dp, dists, sigma, kappa, phi, nh, (unsigned*)Aws);
  gemm_kernel<<<N_OUTP / 64, 512, 0, stream>>>(Aws, Bws, out);
}

// Round 6
// 64.949 us; speedup vs baseline: 1.7277x; 1.7277x over previous
//
#include <hip/hip_runtime.h>
#include <hip/hip_bf16.h>

// Problem constants
#define N_IN   65536
#define N_OUTP 16384
#define KNB    16
#define FDIM   64
#define M_DIM  32          // N_DIST * N_PHI
#define KDIM   2048        // M_DIM * FDIM
#define OUT_D  256

typedef __bf16 bf16x8_t __attribute__((ext_vector_type(8)));
typedef float  f32x4_t  __attribute__((ext_vector_type(4)));

// ---------------------------------------------------------------------------
// A storage ("stream" layout): per 16-row tile T (=row>>4), per K32-chunk kk,
// 64 lanes x 16B. Lane l holds row (l&15), kg in [kk*32+(l>>4)*8, +8).
// u128 index = T*4096 + kk*64 + l.  One 16B chunk = 8 consecutive kg of one
// row = (one m, 8 consecutive f) -> agg threads can emit chunks directly.
// ---------------------------------------------------------------------------

__device__ __forceinline__ unsigned pk2(float a, float b) {
  __bf16 b0 = (__bf16)a, b1 = (__bf16)b;
  return ((unsigned)__builtin_bit_cast(unsigned short, b1) << 16) |
          (unsigned)__builtin_bit_cast(unsigned short, b0);
}

// ---------------------------------------------------------------------------
// pack_B: W_out (2048x256 f32) -> bf16 B-fragments. Chunk c = (kk, nt, lane);
// lane l holds B[kk*32 + (l>>4)*8 + j][nt*16 + (l&15)], j = 0..7.
// ---------------------------------------------------------------------------
__global__ __launch_bounds__(256) void pack_B_kernel(
    const float* __restrict__ W, uint4* __restrict__ Bws)
{
  int c    = blockIdx.x * 256 + threadIdx.x;   // 65536 chunks
  int lane = c & 63;
  int nt   = (c >> 6) & 15;
  int kk   = c >> 10;
  int row0 = kk * 32 + (lane >> 4) * 8;
  int col  = nt * 16 + (lane & 15);
  union { unsigned short s[8]; uint4 v; } u;
#pragma unroll
  for (int j = 0; j < 8; ++j) {
    float f = W[(row0 + j) * OUT_D + col];
    __bf16 b = (__bf16)f;
    u.s[j] = __builtin_bit_cast(unsigned short, b);
  }
  Bws[c] = u.v;
}

// ---------------------------------------------------------------------------
// agg: weights + gather(x->LDS) + 8x8-tiled einsum -> A stream chunks
// written DIRECTLY to global (no LDS transpose). 8 rows/block, 2048 blocks,
// 256 threads, 53.5 KB LDS -> 3 blocks/CU. 2 barriers. All register arrays
// statically indexed (no scratch).
//   wbuf strides: r8*580, k*36  (both ≡4 mod 32 banks -> spread)
//   xbuf strides: r8*1092, k*68, halves at +0/+36 (mid-row pad)
// ---------------------------------------------------------------------------
#define WST 580
#define WKS 36
#define XST 1092
#define XKS 68

__global__ __launch_bounds__(256) void agg_kernel(
    const float* __restrict__ x,
    const float* __restrict__ d_dists,
    const float* __restrict__ d_phi,
    const float* __restrict__ dists,
    const float* __restrict__ sigma_p,
    const float* __restrict__ kappa_p,
    const float* __restrict__ phi,
    const int*   __restrict__ nh_idx,
    uint4*       __restrict__ Aws)     // stream layout
{
  __shared__ __align__(16) float wbuf[8 * WST];   // 18560 B
  __shared__ __align__(16) float xbuf[8 * XST];   // 34944 B

  const int t  = threadIdx.x;
  const int n0 = blockIdx.x * 8;
  const int T  = blockIdx.x >> 1;          // 16-row tile index
  const int r0 = (blockIdx.x & 1) * 8;     // row offset within tile

  // ---- Phase 0a: issue x gather early. thread -> (h=t&1, gk=(t>>1)&15, gr8=t>>5)
  const int h = t & 1, gk = (t >> 1) & 15, gr8 = t >> 5;
  const int gidx = nh_idx[(n0 + gr8) * KNB + gk];
  const float4* xr = (const float4*)x + (size_t)gidx * 16 + h * 8;
  float4 xreg[8];
#pragma unroll
  for (int j = 0; j < 8; ++j) xreg[j] = xr[j];

  // ---- Phase 0b: weights while gather is in flight.
  // thread -> (rk = t>>1: r8 = rk>>4, k = rk&15; rep = t&1)
  {
    const float sinv = 1.0f / sigma_p[0];
    const float kap  = kappa_p[0];
    float phiv[8], distv[4];
#pragma unroll
    for (int p = 0; p < 8; ++p) phiv[p] = phi[p];
#pragma unroll
    for (int d = 0; d < 4; ++d) distv[d] = dists[d];

    int rk = t >> 1, r8 = rk >> 4, k = rk & 15, rep = t & 1;
    int n = n0 + r8;
    float dd = d_dists[n * KNB + k];
    float dp = d_phi[n * KNB + k];
    float wp[8];
#pragma unroll
    for (int p = 0; p < 8; ++p) wp[p] = __expf(kap * __cosf(dp - phiv[p]));
#pragma unroll
    for (int dl = 0; dl < 2; ++dl) {
      int d = rep * 2 + dl;
      float td = (dd - distv[d]) * sinv;
      float wd = __expf(-0.5f * td * td);
      float* dst = wbuf + r8 * WST + k * WKS + d * 8;
      *(float4*)(dst)     = make_float4(wd * wp[0], wd * wp[1], wd * wp[2], wd * wp[3]);
      *(float4*)(dst + 4) = make_float4(wd * wp[4], wd * wp[5], wd * wp[6], wd * wp[7]);
    }
  }

  // ---- Phase 0c: commit gather to xbuf.
  {
    float4* xd = (float4*)(xbuf + gr8 * XST + gk * XKS + h * 36);
#pragma unroll
    for (int j = 0; j < 8; ++j) xd[j] = xreg[j];
  }
  __syncthreads();

  // ---- Phase 1: normalize wbuf in place. thread -> (r8 = t>>5, m = t&31)
  {
    int r8 = t >> 5, m = t & 31;
    float wv[16];
    float s = 0.f;
#pragma unroll
    for (int k = 0; k < 16; ++k) {
      wv[k] = wbuf[r8 * WST + k * WKS + m];
      s += wv[k];
    }
    float wn = 1.0f / (s + 1e-9f);
#pragma unroll
    for (int k = 0; k < 16; ++k)
      wbuf[r8 * WST + k * WKS + m] = wv[k] * wn;
  }
  __syncthreads();

  // ---- Phase 2: einsum 8m x 8f per thread; direct stream-chunk stores.
  // thread -> (r8 = t&7, fo = (t>>3)&7 [f-octet], mq = t>>6 [m-quad of 8])
  {
    const int r8 = t & 7, fo = (t >> 3) & 7, mq = t >> 6;
    float acc[8][8];
#pragma unroll
    for (int mi = 0; mi < 8; ++mi)
#pragma unroll
      for (int fi = 0; fi < 8; ++fi) acc[mi][fi] = 0.f;

    const float* wp_ = wbuf + r8 * WST + mq * 8;
    const float* xp_ = xbuf + r8 * XST + ((fo < 4) ? fo * 8 : 36 + (fo - 4) * 8);

#pragma unroll 4
    for (int k = 0; k < 16; ++k) {
      float4 wa = *(const float4*)(wp_ + k * WKS);
      float4 wb = *(const float4*)(wp_ + k * WKS + 4);
      float4 xa = *(const float4*)(xp_ + k * XKS);
      float4 xb = *(const float4*)(xp_ + k * XKS + 4);
      float wv[8] = {wa.x, wa.y, wa.z, wa.w, wb.x, wb.y, wb.z, wb.w};
      float xv[8] = {xa.x, xa.y, xa.z, xa.w, xb.x, xb.y, xb.z, xb.w};
#pragma unroll
      for (int mi = 0; mi < 8; ++mi)
#pragma unroll
        for (int fi = 0; fi < 8; ++fi)
          acc[mi][fi] += wv[mi] * xv[fi];
    }

    // chunk for (row r0+r8, m = mq*8+mi, f in [fo*8, fo*8+8)):
    // u128 idx = T*4096 + (m*2 + (fo>>2))*64 + (fo&3)*16 + (r0+r8)
    uint4* base = Aws + (size_t)T * 4096 + (fo & 3) * 16 + r0 + r8
                      + (size_t)(fo >> 2) * 64;
#pragma unroll
    for (int mi = 0; mi < 8; ++mi) {
      int m = mq * 8 + mi;
      uint4 v;
      v.x = pk2(acc[mi][0], acc[mi][1]);
      v.y = pk2(acc[mi][2], acc[mi][3]);
      v.z = pk2(acc[mi][4], acc[mi][5]);
      v.w = pk2(acc[mi][6], acc[mi][7]);
      base[m * 128] = v;
    }
  }
}

// ---------------------------------------------------------------------------
// gemm: out(16384x256) = A(stream) @ B(frags). 256 blocks x 512 threads.
// Block = 64 rows x 256 cols; wave w: rows (w&1)*32, cols (w>>1)*64.
// No LDS, no barriers. Depth-4 register pipeline (24 loads in flight).
// ---------------------------------------------------------------------------
__global__ __launch_bounds__(512) void gemm_kernel(
    const uint4* __restrict__ Astream,
    const uint4* __restrict__ Bws,
    float*       __restrict__ out)
{
  const int t    = threadIdx.x;
  const int lane = t & 63;
  const int w    = t >> 6;
  const int rb   = blockIdx.x;

  const uint4* pa = Astream + (size_t)(rb * 4 + (w & 1) * 2) * 4096 + lane;
  const uint4* pb = Bws + ((w >> 1) * 4) * 64 + lane;

  f32x4_t cacc[2][4];
#pragma unroll
  for (int mt = 0; mt < 2; ++mt)
#pragma unroll
    for (int i = 0; i < 4; ++i)
      cacc[mt][i] = (f32x4_t){0.f, 0.f, 0.f, 0.f};

  uint4 a[4][2], b[4][4];
#pragma unroll
  for (int s = 0; s < 4; ++s) {
    a[s][0] = pa[s * 64];
    a[s][1] = pa[4096 + s * 64];
#pragma unroll
    for (int i = 0; i < 4; ++i) b[s][i] = pb[s * 1024 + i * 64];
  }

#pragma unroll 4
  for (int kk = 0; kk < 64; ++kk) {
    const int s = kk & 3;
    bf16x8_t A0 = __builtin_bit_cast(bf16x8_t, a[s][0]);
    bf16x8_t A1 = __builtin_bit_cast(bf16x8_t, a[s][1]);
#pragma unroll
    for (int i = 0; i < 4; ++i) {
      bf16x8_t B = __builtin_bit_cast(bf16x8_t, b[s][i]);
      cacc[0][i] = __builtin_amdgcn_mfma_f32_16x16x32_bf16(A0, B, cacc[0][i], 0, 0, 0);
      cacc[1][i] = __builtin_amdgcn_mfma_f32_16x16x32_bf16(A1, B, cacc[1][i], 0, 0, 0);
    }
    if (kk < 60) {
      a[s][0] = pa[(kk + 4) * 64];
      a[s][1] = pa[4096 + (kk + 4) * 64];
#pragma unroll
      for (int i = 0; i < 4; ++i) b[s][i] = pb[(kk + 4) * 1024 + i * 64];
    }
  }

  // C/D layout: col = lane&15, row = (lane>>4)*4 + reg
  const int rbase = rb * 64 + (w & 1) * 32 + (lane >> 4) * 4;
  const int cbase = (w >> 1) * 64 + (lane & 15);
#pragma unroll
  for (int mt = 0; mt < 2; ++mt)
#pragma unroll
    for (int i = 0; i < 4; ++i)
#pragma unroll
      for (int reg = 0; reg < 4; ++reg)
        out[(rbase + mt * 16 + reg) * OUT_D + cbase + i * 16] = cacc[mt][i][reg];
}

// ===========================================================================
extern "C" void kernel_launch(void* const* d_in, const int* in_sizes, int n_in,
                              void* d_out, int out_size, void* d_ws, size_t ws_size,
                              hipStream_t stream) {
  const float* x      = (const float*)d_in[0];
  const float* dd     = (const float*)d_in[1];
  const float* dp     = (const float*)d_in[2];
  const float* dists  = (const float*)d_in[3];
  const float* sigma  = (const float*)d_in[4];
  const float* kappa  = (const float*)d_in[5];
  const float* phi    = (const float*)d_in[6];
  const float* W      = (const float*)d_in[7];
  const int*   nh     = (const int*)d_in[8];
  float*       out    = (float*)d_out;

  uint4* Bws = (uint4*)d_ws;                       // 1 MB of B-fragments
  uint4* Aws = (uint4*)((char*)d_ws + (1 << 20));  // 64 MB A, stream layout

  pack_B_kernel<<<256, 256, 0, stream>>>(W, Bws);
  agg_kernel<<<N_OUTP / 8, 256, 0, stream>>>(
      x, dd, dp, dists, sigma, kappa, phi, nh, Aws);
  gemm_kernel<<<N_OUTP / 64, 512, 0, stream>>>(Aws, Bws, out);
}

// Round 7
// 62.750 us; speedup vs baseline: 1.7882x; 1.0350x over previous
//
#include <hip/hip_runtime.h>
#include <hip/hip_bf16.h>

// Problem constants
#define N_IN   65536
#define N_OUTP 16384
#define KNB    16
#define FDIM   64
#define M_DIM  32          // N_DIST * N_PHI
#define KDIM   2048        // M_DIM * FDIM
#define OUT_D  256

typedef __bf16 bf16x8_t __attribute__((ext_vector_type(8)));
typedef float  f32x4_t  __attribute__((ext_vector_type(4)));
typedef float  f32x2_t  __attribute__((ext_vector_type(2)));

// ---------------------------------------------------------------------------
// A storage ("stream" layout): per 16-row tile T (=row>>4), per K32-chunk kk,
// 64 lanes x 16B. Lane l holds row (l&15), kg in [kk*32+(l>>4)*8, +8).
// u128 index = T*4096 + kk*64 + l.
// ---------------------------------------------------------------------------

__device__ __forceinline__ unsigned pk2(float a, float b) {
  __bf16 b0 = (__bf16)a, b1 = (__bf16)b;
  return ((unsigned)__builtin_bit_cast(unsigned short, b1) << 16) |
          (unsigned)__builtin_bit_cast(unsigned short, b0);
}

// ---------------------------------------------------------------------------
// pack_B v2: one block per K32-slab (64 blocks). Coalesced float4 load of
// W rows [kk*32,+32) into padded LDS, then emit bf16 B-fragments coalesced.
// Chunk c=(kk,nt,lane): lane l holds B[kk*32+(l>>4)*8+j][nt*16+(l&15)].
// ---------------------------------------------------------------------------
__global__ __launch_bounds__(256) void pack_B_kernel(
    const float* __restrict__ W, uint4* __restrict__ Bws)
{
  __shared__ float wlds[32 * 260];
  const int kk = blockIdx.x;
  const int t  = threadIdx.x;

  const float4* Wb = (const float4*)(W + kk * 32 * OUT_D);
#pragma unroll
  for (int i = 0; i < 8; ++i) {
    int idx = i * 256 + t;            // 2048 float4 = 32 rows x 64 col4
    int row = idx >> 6, c4 = idx & 63;
    float4 v = Wb[idx];
    *(float4*)(wlds + row * 260 + c4 * 4) = v;
  }
  __syncthreads();

#pragma unroll
  for (int j = 0; j < 4; ++j) {
    int c  = j * 256 + t;             // chunk within slab, 0..1023
    int l  = c & 63, nt = c >> 6;
    int r0 = (l >> 4) * 8, col = nt * 16 + (l & 15);
    union { unsigned short s[8]; uint4 v; } u;
#pragma unroll
    for (int jj = 0; jj < 8; ++jj) {
      __bf16 b = (__bf16)wlds[(r0 + jj) * 260 + col];
      u.s[jj] = __builtin_bit_cast(unsigned short, b);
    }
    Bws[(size_t)kk * 1024 + c] = u.v;
  }
}

// ---------------------------------------------------------------------------
// agg: weights + gather(x->LDS) + 8x8-tiled einsum (packed f32x2 FMA) ->
// A stream chunks written directly to global. 8 rows/block, 2048 blocks,
// 256 threads, 53.5 KB LDS -> 3 blocks/CU, 2 barriers, no scratch.
// ---------------------------------------------------------------------------
#define WST 580
#define WKS 36
#define XST 1092
#define XKS 68

__global__ __launch_bounds__(256) void agg_kernel(
    const float* __restrict__ x,
    const float* __restrict__ d_dists,
    const float* __restrict__ d_phi,
    const float* __restrict__ dists,
    const float* __restrict__ sigma_p,
    const float* __restrict__ kappa_p,
    const float* __restrict__ phi,
    const int*   __restrict__ nh_idx,
    uint4*       __restrict__ Aws)     // stream layout
{
  __shared__ __align__(16) float wbuf[8 * WST];   // 18560 B
  __shared__ __align__(16) float xbuf[8 * XST];   // 34944 B

  const int t  = threadIdx.x;
  const int n0 = blockIdx.x * 8;
  const int T  = blockIdx.x >> 1;          // 16-row tile index
  const int r0 = (blockIdx.x & 1) * 8;     // row offset within tile

  // ---- Phase 0a: issue x gather early.
  const int h = t & 1, gk = (t >> 1) & 15, gr8 = t >> 5;
  const int gidx = nh_idx[(n0 + gr8) * KNB + gk];
  const float4* xr = (const float4*)x + (size_t)gidx * 16 + h * 8;
  float4 xreg[8];
#pragma unroll
  for (int j = 0; j < 8; ++j) xreg[j] = xr[j];

  // ---- Phase 0b: weights while gather is in flight.
  {
    const float sinv = 1.0f / sigma_p[0];
    const float kap  = kappa_p[0];
    float phiv[8], distv[4];
#pragma unroll
    for (int p = 0; p < 8; ++p) phiv[p] = phi[p];
#pragma unroll
    for (int d = 0; d < 4; ++d) distv[d] = dists[d];

    int rk = t >> 1, r8 = rk >> 4, k = rk & 15, rep = t & 1;
    int n = n0 + r8;
    float dd = d_dists[n * KNB + k];
    float dp = d_phi[n * KNB + k];
    float wp[8];
#pragma unroll
    for (int p = 0; p < 8; ++p) wp[p] = __expf(kap * __cosf(dp - phiv[p]));
#pragma unroll
    for (int dl = 0; dl < 2; ++dl) {
      int d = rep * 2 + dl;
      float td = (dd - distv[d]) * sinv;
      float wd = __expf(-0.5f * td * td);
      float* dst = wbuf + r8 * WST + k * WKS + d * 8;
      *(float4*)(dst)     = make_float4(wd * wp[0], wd * wp[1], wd * wp[2], wd * wp[3]);
      *(float4*)(dst + 4) = make_float4(wd * wp[4], wd * wp[5], wd * wp[6], wd * wp[7]);
    }
  }

  // ---- Phase 0c: commit gather to xbuf.
  {
    float4* xd = (float4*)(xbuf + gr8 * XST + gk * XKS + h * 36);
#pragma unroll
    for (int j = 0; j < 8; ++j) xd[j] = xreg[j];
  }
  __syncthreads();

  // ---- Phase 1: normalize wbuf in place. thread -> (r8 = t>>5, m = t&31)
  {
    int r8 = t >> 5, m = t & 31;
    float wv[16];
    float s = 0.f;
#pragma unroll
    for (int k = 0; k < 16; ++k) {
      wv[k] = wbuf[r8 * WST + k * WKS + m];
      s += wv[k];
    }
    float wn = 1.0f / (s + 1e-9f);
#pragma unroll
    for (int k = 0; k < 16; ++k)
      wbuf[r8 * WST + k * WKS + m] = wv[k] * wn;
  }
  __syncthreads();

  // ---- Phase 2: einsum 8m x 8f per thread (f32x2 packed FMA);
  // thread -> (r8 = t&7, fo = (t>>3)&7 [f-octet], mq = t>>6 [m-quad of 8])
  {
    const int r8 = t & 7, fo = (t >> 3) & 7, mq = t >> 6;
    f32x2_t acc[8][4];
#pragma unroll
    for (int mi = 0; mi < 8; ++mi)
#pragma unroll
      for (int fj = 0; fj < 4; ++fj) acc[mi][fj] = (f32x2_t){0.f, 0.f};

    const float* wp_ = wbuf + r8 * WST + mq * 8;
    const float* xp_ = xbuf + r8 * XST + ((fo < 4) ? fo * 8 : 36 + (fo - 4) * 8);

#pragma unroll 8
    for (int k = 0; k < 16; ++k) {
      float4 wa = *(const float4*)(wp_ + k * WKS);
      float4 wb = *(const float4*)(wp_ + k * WKS + 4);
      float4 xa = *(const float4*)(xp_ + k * XKS);
      float4 xb = *(const float4*)(xp_ + k * XKS + 4);
      float wv[8] = {wa.x, wa.y, wa.z, wa.w, wb.x, wb.y, wb.z, wb.w};
      f32x2_t xv[4] = {(f32x2_t){xa.x, xa.y}, (f32x2_t){xa.z, xa.w},
                       (f32x2_t){xb.x, xb.y}, (f32x2_t){xb.z, xb.w}};
#pragma unroll
      for (int mi = 0; mi < 8; ++mi) {
        f32x2_t wm = (f32x2_t){wv[mi], wv[mi]};
#pragma unroll
        for (int fj = 0; fj < 4; ++fj)
          acc[mi][fj] += wm * xv[fj];
      }
    }

    // chunk for (row r0+r8, m = mq*8+mi, f in [fo*8, fo*8+8)):
    // u128 idx = T*4096 + (m*2 + (fo>>2))*64 + (fo&3)*16 + (r0+r8)
    uint4* base = Aws + (size_t)T * 4096 + (fo & 3) * 16 + r0 + r8
                      + (size_t)(fo >> 2) * 64;
#pragma unroll
    for (int mi = 0; mi < 8; ++mi) {
      int m = mq * 8 + mi;
      uint4 v;
      v.x = pk2(acc[mi][0][0], acc[mi][0][1]);
      v.y = pk2(acc[mi][1][0], acc[mi][1][1]);
      v.z = pk2(acc[mi][2][0], acc[mi][2][1]);
      v.w = pk2(acc[mi][3][0], acc[mi][3][1]);
      base[m * 128] = v;
    }
  }
}

// ---------------------------------------------------------------------------
// gemm v3: out(16384x256) = A(stream) @ B(frags). 256 blocks x 256 threads.
// Block = 64 rows x 256 cols; wave w covers rows 0..63 x cols w*64..+63
// (cacc[4][4] of 16x16 tiles). A shared across waves via L2; per-wave
// ingest 8KB / 16 MFMA (was 6KB / 8). Depth-2 register prefetch.
// ---------------------------------------------------------------------------
__global__ __launch_bounds__(256) void gemm_kernel(
    const uint4* __restrict__ Astream,
    const uint4* __restrict__ Bws,
    float*       __restrict__ out)
{
  const int t    = threadIdx.x;
  const int lane = t & 63;
  const int w    = t >> 6;       // col group 0..3
  const int rb   = blockIdx.x;   // 64-row block

  const uint4* pa = Astream + (size_t)(rb * 4) * 4096 + lane;
  const uint4* pb = Bws + (w * 4) * 64 + lane;

  f32x4_t cacc[4][4];
#pragma unroll
  for (int mt = 0; mt < 4; ++mt)
#pragma unroll
    for (int i = 0; i < 4; ++i)
      cacc[mt][i] = (f32x4_t){0.f, 0.f, 0.f, 0.f};

  uint4 a[2][4], b[2][4];
#pragma unroll
  for (int s = 0; s < 2; ++s) {
#pragma unroll
    for (int mt = 0; mt < 4; ++mt) a[s][mt] = pa[mt * 4096 + s * 64];
#pragma unroll
    for (int i = 0; i < 4; ++i)    b[s][i]  = pb[s * 1024 + i * 64];
  }

#pragma unroll 4
  for (int kk = 0; kk < 64; ++kk) {
    const int s = kk & 1;
    bf16x8_t B0 = __builtin_bit_cast(bf16x8_t, b[s][0]);
    bf16x8_t B1 = __builtin_bit_cast(bf16x8_t, b[s][1]);
    bf16x8_t B2 = __builtin_bit_cast(bf16x8_t, b[s][2]);
    bf16x8_t B3 = __builtin_bit_cast(bf16x8_t, b[s][3]);
#pragma unroll
    for (int mt = 0; mt < 4; ++mt) {
      bf16x8_t A = __builtin_bit_cast(bf16x8_t, a[s][mt]);
      cacc[mt][0] = __builtin_amdgcn_mfma_f32_16x16x32_bf16(A, B0, cacc[mt][0], 0, 0, 0);
      cacc[mt][1] = __builtin_amdgcn_mfma_f32_16x16x32_bf16(A, B1, cacc[mt][1], 0, 0, 0);
      cacc[mt][2] = __builtin_amdgcn_mfma_f32_16x16x32_bf16(A, B2, cacc[mt][2], 0, 0, 0);
      cacc[mt][3] = __builtin_amdgcn_mfma_f32_16x16x32_bf16(A, B3, cacc[mt][3], 0, 0, 0);
    }
    if (kk < 62) {
#pragma unroll
      for (int mt = 0; mt < 4; ++mt) a[s][mt] = pa[mt * 4096 + (kk + 2) * 64];
#pragma unroll
      for (int i = 0; i < 4; ++i)    b[s][i]  = pb[(kk + 2) * 1024 + i * 64];
    }
  }

  // C/D layout: col = lane&15, row = (lane>>4)*4 + reg
  const int rbase = rb * 64 + (lane >> 4) * 4;
  const int cbase = w * 64 + (lane & 15);
#pragma unroll
  for (int mt = 0; mt < 4; ++mt)
#pragma unroll
    for (int i = 0; i < 4; ++i)
#pragma unroll
      for (int reg = 0; reg < 4; ++reg)
        out[(rbase + mt * 16 + reg) * OUT_D + cbase + i * 16] = cacc[mt][i][reg];
}

// ===========================================================================
extern "C" void kernel_launch(void* const* d_in, const int* in_sizes, int n_in,
                              void* d_out, int out_size, void* d_ws, size_t ws_size,
                              hipStream_t stream) {
  const float* x      = (const float*)d_in[0];
  const float* dd     = (const float*)d_in[1];
  const float* dp     = (const float*)d_in[2];
  const float* dists  = (const float*)d_in[3];
  const float* sigma  = (const float*)d_in[4];
  const float* kappa  = (const float*)d_in[5];
  const float* phi    = (const float*)d_in[6];
  const float* W      = (const float*)d_in[7];
  const int*   nh     = (const int*)d_in[8];
  float*       out    = (float*)d_out;

  uint4* Bws = (uint4*)d_ws;                       // 1 MB of B-fragments
  uint4* Aws = (uint4*)((char*)d_ws + (1 << 20));  // 64 MB A, stream layout

  pack_B_kernel<<<64, 256, 0, stream>>>(W, Bws);
  agg_kernel<<<N_OUTP / 8, 256, 0, stream>>>(
      x, dd, dp, dists, sigma, kappa, phi, nh, Aws);
  gemm_kernel<<<N_OUTP / 64, 256, 0, stream>>>(Aws, Bws, out);
}

// Round 8
// 60.621 us; speedup vs baseline: 1.8510x; 1.0351x over previous
//
#include <hip/hip_runtime.h>
#include <hip/hip_bf16.h>

// Problem constants
#define N_IN   65536
#define N_OUTP 16384
#define KNB    16
#define FDIM   64
#define M_DIM  32          // N_DIST * N_PHI
#define KDIM   2048        // M_DIM * FDIM
#define OUT_D  256

typedef __bf16 bf16x8_t __attribute__((ext_vector_type(8)));
typedef float  f32x4_t  __attribute__((ext_vector_type(4)));
typedef float  f32x2_t  __attribute__((ext_vector_type(2)));

// ---------------------------------------------------------------------------
// A storage ("stream" layout): per 16-row tile T (=row>>4), per K32-chunk kk,
// 64 lanes x 16B. Lane l holds row (l&15), kg in [kk*32+(l>>4)*8, +8).
// u128 index = T*4096 + kk*64 + l.
// ---------------------------------------------------------------------------

__device__ __forceinline__ unsigned pk2(float a, float b) {
  __bf16 b0 = (__bf16)a, b1 = (__bf16)b;
  return ((unsigned)__builtin_bit_cast(unsigned short, b1) << 16) |
          (unsigned)__builtin_bit_cast(unsigned short, b0);
}

// ---------------------------------------------------------------------------
// pack_B v2: one block per K32-slab (64 blocks). Coalesced float4 load of
// W rows [kk*32,+32) into padded LDS, then emit bf16 B-fragments coalesced.
// Chunk c=(kk,nt,lane): lane l holds B[kk*32+(l>>4)*8+j][nt*16+(l&15)].
// ---------------------------------------------------------------------------
__global__ __launch_bounds__(256) void pack_B_kernel(
    const float* __restrict__ W, uint4* __restrict__ Bws)
{
  __shared__ float wlds[32 * 260];
  const int kk = blockIdx.x;
  const int t  = threadIdx.x;

  const float4* Wb = (const float4*)(W + kk * 32 * OUT_D);
#pragma unroll
  for (int i = 0; i < 8; ++i) {
    int idx = i * 256 + t;            // 2048 float4 = 32 rows x 64 col4
    int row = idx >> 6, c4 = idx & 63;
    float4 v = Wb[idx];
    *(float4*)(wlds + row * 260 + c4 * 4) = v;
  }
  __syncthreads();

#pragma unroll
  for (int j = 0; j < 4; ++j) {
    int c  = j * 256 + t;             // chunk within slab, 0..1023
    int l  = c & 63, nt = c >> 6;
    int r0 = (l >> 4) * 8, col = nt * 16 + (l & 15);
    union { unsigned short s[8]; uint4 v; } u;
#pragma unroll
    for (int jj = 0; jj < 8; ++jj) {
      __bf16 b = (__bf16)wlds[(r0 + jj) * 260 + col];
      u.s[jj] = __builtin_bit_cast(unsigned short, b);
    }
    Bws[(size_t)kk * 1024 + c] = u.v;
  }
}

// ---------------------------------------------------------------------------
// agg: weights + gather(x->LDS) + 8x8-tiled einsum (packed f32x2 FMA) ->
// A stream chunks written directly to global. 8 rows/block, 2048 blocks,
// 256 threads, ~52 KB LDS -> 3 blocks/CU, 2 barriers, no scratch.
// ---------------------------------------------------------------------------
#define WST 580
#define WKS 36
#define XST 1092
#define XKS 68

__global__ __launch_bounds__(256) void agg_kernel(
    const float* __restrict__ x,
    const float* __restrict__ d_dists,
    const float* __restrict__ d_phi,
    const float* __restrict__ dists,
    const float* __restrict__ sigma_p,
    const float* __restrict__ kappa_p,
    const float* __restrict__ phi,
    const int*   __restrict__ nh_idx,
    uint4*       __restrict__ Aws)     // stream layout
{
  __shared__ __align__(16) float wbuf[8 * WST];   // 18560 B
  __shared__ __align__(16) float xbuf[8 * XST];   // 34944 B

  const int t  = threadIdx.x;
  const int n0 = blockIdx.x * 8;
  const int T  = blockIdx.x >> 1;          // 16-row tile index
  const int r0 = (blockIdx.x & 1) * 8;     // row offset within tile

  // ---- Phase 0a: issue x gather early.
  const int h = t & 1, gk = (t >> 1) & 15, gr8 = t >> 5;
  const int gidx = nh_idx[(n0 + gr8) * KNB + gk];
  const float4* xr = (const float4*)x + (size_t)gidx * 16 + h * 8;
  float4 xreg[8];
#pragma unroll
  for (int j = 0; j < 8; ++j) xreg[j] = xr[j];

  // ---- Phase 0b: weights while gather is in flight.
  {
    const float sinv = 1.0f / sigma_p[0];
    const float kap  = kappa_p[0];
    float phiv[8], distv[4];
#pragma unroll
    for (int p = 0; p < 8; ++p) phiv[p] = phi[p];
#pragma unroll
    for (int d = 0; d < 4; ++d) distv[d] = dists[d];

    int rk = t >> 1, r8 = rk >> 4, k = rk & 15, rep = t & 1;
    int n = n0 + r8;
    float dd = d_dists[n * KNB + k];
    float dp = d_phi[n * KNB + k];
    float wp[8];
#pragma unroll
    for (int p = 0; p < 8; ++p) wp[p] = __expf(kap * __cosf(dp - phiv[p]));
#pragma unroll
    for (int dl = 0; dl < 2; ++dl) {
      int d = rep * 2 + dl;
      float td = (dd - distv[d]) * sinv;
      float wd = __expf(-0.5f * td * td);
      float* dst = wbuf + r8 * WST + k * WKS + d * 8;
      *(float4*)(dst)     = make_float4(wd * wp[0], wd * wp[1], wd * wp[2], wd * wp[3]);
      *(float4*)(dst + 4) = make_float4(wd * wp[4], wd * wp[5], wd * wp[6], wd * wp[7]);
    }
  }

  // ---- Phase 0c: commit gather to xbuf.
  {
    float4* xd = (float4*)(xbuf + gr8 * XST + gk * XKS + h * 36);
#pragma unroll
    for (int j = 0; j < 8; ++j) xd[j] = xreg[j];
  }
  __syncthreads();

  // ---- Phase 1: normalize wbuf in place. thread -> (r8 = t>>5, m = t&31)
  {
    int r8 = t >> 5, m = t & 31;
    float wv[16];
    float s = 0.f;
#pragma unroll
    for (int k = 0; k < 16; ++k) {
      wv[k] = wbuf[r8 * WST + k * WKS + m];
      s += wv[k];
    }
    float wn = 1.0f / (s + 1e-9f);
#pragma unroll
    for (int k = 0; k < 16; ++k)
      wbuf[r8 * WST + k * WKS + m] = wv[k] * wn;
  }
  __syncthreads();

  // ---- Phase 2: einsum 8m x 8f per thread (f32x2 packed FMA);
  // thread -> (r8 = t&7, fo = (t>>3)&7 [f-octet], mq = t>>6 [m-quad of 8])
  {
    const int r8 = t & 7, fo = (t >> 3) & 7, mq = t >> 6;
    f32x2_t acc[8][4];
#pragma unroll
    for (int mi = 0; mi < 8; ++mi)
#pragma unroll
      for (int fj = 0; fj < 4; ++fj) acc[mi][fj] = (f32x2_t){0.f, 0.f};

    const float* wp_ = wbuf + r8 * WST + mq * 8;
    const float* xp_ = xbuf + r8 * XST + ((fo < 4) ? fo * 8 : 36 + (fo - 4) * 8);

#pragma unroll 8
    for (int k = 0; k < 16; ++k) {
      float4 wa = *(const float4*)(wp_ + k * WKS);
      float4 wb = *(const float4*)(wp_ + k * WKS + 4);
      float4 xa = *(const float4*)(xp_ + k * XKS);
      float4 xb = *(const float4*)(xp_ + k * XKS + 4);
      float wv[8] = {wa.x, wa.y, wa.z, wa.w, wb.x, wb.y, wb.z, wb.w};
      f32x2_t xv[4] = {(f32x2_t){xa.x, xa.y}, (f32x2_t){xa.z, xa.w},
                       (f32x2_t){xb.x, xb.y}, (f32x2_t){xb.z, xb.w}};
#pragma unroll
      for (int mi = 0; mi < 8; ++mi) {
        f32x2_t wm = (f32x2_t){wv[mi], wv[mi]};
#pragma unroll
        for (int fj = 0; fj < 4; ++fj)
          acc[mi][fj] += wm * xv[fj];
      }
    }

    // chunk for (row r0+r8, m = mq*8+mi, f in [fo*8, fo*8+8)):
    // u128 idx = T*4096 + (m*2 + (fo>>2))*64 + (fo&3)*16 + (r0+r8)
    uint4* base = Aws + (size_t)T * 4096 + (fo & 3) * 16 + r0 + r8
                      + (size_t)(fo >> 2) * 64;
#pragma unroll
    for (int mi = 0; mi < 8; ++mi) {
      int m = mq * 8 + mi;
      uint4 v;
      v.x = pk2(acc[mi][0][0], acc[mi][0][1]);
      v.y = pk2(acc[mi][1][0], acc[mi][1][1]);
      v.z = pk2(acc[mi][2][0], acc[mi][2][1]);
      v.w = pk2(acc[mi][3][0], acc[mi][3][1]);
      base[m * 128] = v;
    }
  }
}

// ---------------------------------------------------------------------------
// gemm v4 (K-split wave pairs): out(16384x256) = A(stream) @ B(frags).
// 256 blocks x 512 threads. Block = 64 rows x 256 cols. Wave w:
//   cg = w&3 (64-col group), half = w>>2 (kk parity). Each wave: 32 j-iters,
//   kk = 2j+half, cacc[4][4], 16 MFMA per iter, depth-4 register prefetch.
// Epilogue: half=0 parks partials in padded LDS (stride 68, conflict-free);
// one barrier; half=1 adds and stores. 8 waves resident = 2/SIMD.
// ---------------------------------------------------------------------------
__global__ __launch_bounds__(512, 2) void gemm_kernel(
    const uint4* __restrict__ Astream,
    const uint4* __restrict__ Bws,
    float*       __restrict__ out)
{
  __shared__ float red[4][64 * 68];   // 69632 B

  const int t    = threadIdx.x;
  const int lane = t & 63;
  const int w    = t >> 6;
  const int cg   = w & 3;        // col group (64 cols)
  const int half = w >> 2;       // kk parity
  const int rb   = blockIdx.x;   // 64-row block

  // A: chunk idx = (rb*4+mt)*4096 + kk*64 + lane, kk = 2j+half
  const uint4* pa = Astream + (size_t)(rb * 4) * 4096 + half * 64 + lane;
  // B: chunk idx = kk*1024 + (cg*4+i)*64 + lane
  const uint4* pb = Bws + (half * 16 + cg * 4) * 64 + lane;

  f32x4_t cacc[4][4];
#pragma unroll
  for (int mt = 0; mt < 4; ++mt)
#pragma unroll
    for (int i = 0; i < 4; ++i)
      cacc[mt][i] = (f32x4_t){0.f, 0.f, 0.f, 0.f};

  uint4 a[4][4], b[4][4];
#pragma unroll
  for (int s = 0; s < 4; ++s) {
#pragma unroll
    for (int mt = 0; mt < 4; ++mt) a[s][mt] = pa[mt * 4096 + s * 128];
#pragma unroll
    for (int i = 0; i < 4; ++i)    b[s][i]  = pb[s * 2048 + i * 64];
  }

#pragma unroll 4
  for (int j = 0; j < 32; ++j) {
    const int s = j & 3;
    bf16x8_t B0 = __builtin_bit_cast(bf16x8_t, b[s][0]);
    bf16x8_t B1 = __builtin_bit_cast(bf16x8_t, b[s][1]);
    bf16x8_t B2 = __builtin_bit_cast(bf16x8_t, b[s][2]);
    bf16x8_t B3 = __builtin_bit_cast(bf16x8_t, b[s][3]);
#pragma unroll
    for (int mt = 0; mt < 4; ++mt) {
      bf16x8_t A = __builtin_bit_cast(bf16x8_t, a[s][mt]);
      cacc[mt][0] = __builtin_amdgcn_mfma_f32_16x16x32_bf16(A, B0, cacc[mt][0], 0, 0, 0);
      cacc[mt][1] = __builtin_amdgcn_mfma_f32_16x16x32_bf16(A, B1, cacc[mt][1], 0, 0, 0);
      cacc[mt][2] = __builtin_amdgcn_mfma_f32_16x16x32_bf16(A, B2, cacc[mt][2], 0, 0, 0);
      cacc[mt][3] = __builtin_amdgcn_mfma_f32_16x16x32_bf16(A, B3, cacc[mt][3], 0, 0, 0);
    }
    if (j < 28) {
#pragma unroll
      for (int mt = 0; mt < 4; ++mt) a[s][mt] = pa[mt * 4096 + (j + 4) * 128];
#pragma unroll
      for (int i = 0; i < 4; ++i)    b[s][i]  = pb[(j + 4) * 2048 + i * 64];
    }
  }

  // C/D layout per 16x16 tile: col = lane&15, row = (lane>>4)*4 + reg
  const int lrow = (lane >> 4) * 4;
  const int lcol = lane & 15;

  if (half == 0) {
#pragma unroll
    for (int mt = 0; mt < 4; ++mt)
#pragma unroll
      for (int i = 0; i < 4; ++i)
#pragma unroll
        for (int reg = 0; reg < 4; ++reg)
          red[cg][(mt * 16 + lrow + reg) * 68 + i * 16 + lcol] = cacc[mt][i][reg];
  }
  __syncthreads();
  if (half == 1) {
#pragma unroll
    for (int mt = 0; mt < 4; ++mt)
#pragma unroll
      for (int i = 0; i < 4; ++i)
#pragma unroll
        for (int reg = 0; reg < 4; ++reg) {
          int row = mt * 16 + lrow + reg;
          int col = i * 16 + lcol;
          float v = red[cg][row * 68 + col] + cacc[mt][i][reg];
          out[(rb * 64 + row) * OUT_D + cg * 64 + col] = v;
        }
  }
}

// ===========================================================================
extern "C" void kernel_launch(void* const* d_in, const int* in_sizes, int n_in,
                              void* d_out, int out_size, void* d_ws, size_t ws_size,
                              hipStream_t stream) {
  const float* x      = (const float*)d_in[0];
  const float* dd     = (const float*)d_in[1];
  const float* dp     = (const float*)d_in[2];
  const float* dists  = (const float*)d_in[3];
  const float* sigma  = (const float*)d_in[4];
  const float* kappa  = (const float*)d_in[5];
  const float* phi    = (const float*)d_in[6];
  const float* W      = (const float*)d_in[7];
  const int*   nh     = (const int*)d_in[8];
  float*       out    = (float*)d_out;

  uint4* Bws = (uint4*)d_ws;                       // 1 MB of B-fragments
  uint4* Aws = (uint4*)((char*)d_ws + (1 << 20));  // 64 MB A, stream layout

  pack_B_kernel<<<64, 256, 0, stream>>>(W, Bws);
  agg_kernel<<<N_OUTP / 8, 256, 0, stream>>>(
      x, dd, dp, dists, sigma, kappa, phi, nh, Aws);
  gemm_kernel<<<N_OUTP / 64, 512, 0, stream>>>(Aws, Bws, out);
}